// Round 4
// baseline (136.401 us; speedup 1.0000x reference)
//
#include <hip/hip_runtime.h>
#include <stdint.h>

// out[t][n] = (sum_k q8(x[t]/sq)[k] * w8[n][k]) * a_scale[t] * (wclip[n]/127) + bias[n]
#define T_TOK  32768
#define NIN    1024
#define NOUT   1024
#define BM     64     // tokens per tile
#define NTILES 2      // tiles per block (persistent); grid = 32768/(64*2) = 256
#define NTHR   512    // 8 waves; wave owns 128 n (4 nt), all 64 t (2 mt)

typedef int v4i  __attribute__((ext_vector_type(4)));
typedef int v16i __attribute__((ext_vector_type(16)));

#define MFMA_I8(a, b, c) __builtin_amdgcn_mfma_i32_32x32x32_i8(a, b, c, 0, 0, 0)

// ---------------------------------------------------------------------------
// K0: repack weight (int32 [NOUT][NIN]) into MFMA fragment order:
//   chunk(ntile,ks,lane) holds W[ntile*32+(lane&31)][ks*32+(lane>>5)*16 .. +15]
// so a B-frag load is one coalesced global_load_dwordx4 at base + lane*16.
// ---------------------------------------------------------------------------
__global__ __launch_bounds__(256) void repack_w_frag(const int* __restrict__ w,
                                                     uint32_t* __restrict__ wf) {
  const int gid  = blockIdx.x * 256 + threadIdx.x;  // 65536 chunks of 16B
  const int lane = gid & 63;
  const int ks   = (gid >> 6) & 31;
  const int nt   = gid >> 11;
  const int n    = nt * 32 + (lane & 31);
  const int kb   = ks * 32 + (lane >> 5) * 16;
  const int* src = w + (size_t)n * NIN + kb;
  uint32_t d[4];
#pragma unroll
  for (int q = 0; q < 4; ++q) {
    const int4 v = ((const int4*)src)[q];
    d[q] = (uint32_t)(v.x & 0xff) | ((uint32_t)(v.y & 0xff) << 8) |
           ((uint32_t)(v.z & 0xff) << 16) | ((uint32_t)(v.w & 0xff) << 24);
  }
  ((uint4*)wf)[gid] = make_uint4(d[0], d[1], d[2], d[3]);
}

// ---------------------------------------------------------------------------
// K1: persistent fused quant + GEMM + dequant, double-buffered A in LDS.
// Pipeline per tile: {issue next-tile x loads} interleaved at 8-k-step
// granularity with the current tile's MFMA K-loop (T14 issue-early /
// write-late); quantize+swizzled-LDS-write happens one segment after issue.
// A-LDS swizzle (verified r3): token t, half h, kstep ks stored at chunk
// (mt*32+ks)*64 + (((t&31)^(ks&7)) + 32h); read at lane^(ks&7) -> lane gets
// token lane&31 conflict-free both sides.
// ---------------------------------------------------------------------------
__global__ __launch_bounds__(NTHR, 2) void fused_w8a8(
    const float* __restrict__ x,      // [T_TOK][NIN]
    const uint8_t* __restrict__ wf,   // fragment-ordered weight, 1 MB
    const float* __restrict__ sq,     // [NIN]
    const float* __restrict__ wclip,  // [NOUT]
    const float* __restrict__ bias,   // [NOUT]
    float* __restrict__ out)          // [T_TOK][NOUT]
{
  __shared__ __align__(16) uint8_t Af[2][BM * NIN];   // 2 x 64 KiB
  __shared__ float ascale_s[2][BM];

  const int tid    = threadIdx.x;
  const int lane   = tid & 63;
  const int w      = tid >> 6;                 // 0..7
  const int base_t = blockIdx.x * (BM * NTILES);

  const uint8_t* wfw = wf + ((size_t)(w * 4) * 32 * 64) * 16;  // wave ntile base

  v16i acc[2][4] = {};
  v4i  Ba[4], Bb[4];
  float4 xq0[4], xq1[4];     // staged raw x for the 2 tokens of current group
  int qt0 = 0, qt1 = 0;      // their local token ids (0..63)

  auto ldB = [&](int ks, int nt) -> v4i {
    return *(const v4i*)(wfw + ((((nt * 32 + ks) * 64) + lane) << 4));
  };
  // ksl must be the compile-time (ks & 7)
  auto ldA = [&](int bufi, int mt, int ks, int ksl) -> v4i {
    return *(const v4i*)(&Af[bufi][(((mt * 32 + ks) * 64) + (lane ^ ksl)) << 4]);
  };

  auto issue_group = [&](int tile_t0, int g) {
    qt0 = w * 8 + g * 2;
    qt1 = qt0 + 1;
    const float4* xr0 = (const float4*)(x + (size_t)(tile_t0 + qt0) * NIN);
    const float4* xr1 = (const float4*)(x + (size_t)(tile_t0 + qt1) * NIN);
#pragma unroll
    for (int j = 0; j < 4; ++j) {
      xq0[j] = xr0[j * 64 + lane];
      xq1[j] = xr1[j * 64 + lane];
    }
  };

  auto quant_one = [&](int nbuf, int tl, const float4* vraw, const float4* rs) {
    float4 sv[4];
    float m = 0.f;
#pragma unroll
    for (int j = 0; j < 4; ++j) {
      float4 a = vraw[j];
      a.x *= rs[j].x; a.y *= rs[j].y; a.z *= rs[j].z; a.w *= rs[j].w;
      sv[j] = a;
      m = fmaxf(m, fmaxf(fmaxf(fabsf(a.x), fabsf(a.y)),
                         fmaxf(fabsf(a.z), fabsf(a.w))));
    }
#pragma unroll
    for (int off = 1; off < 64; off <<= 1) m = fmaxf(m, __shfl_xor(m, off));
    const float as = fmaxf(m * (1.f / 127.f), 1e-8f);
    if (lane == 0) ascale_s[nbuf][tl] = as;
    const float ia = __builtin_amdgcn_rcpf(as);
    const int mt = tl >> 5;
#pragma unroll
    for (int j = 0; j < 4; ++j) {
      const int q0 = (int)rintf(fminf(fmaxf(sv[j].x * ia, -127.f), 127.f));
      const int q1 = (int)rintf(fminf(fmaxf(sv[j].y * ia, -127.f), 127.f));
      const int q2 = (int)rintf(fminf(fmaxf(sv[j].z * ia, -127.f), 127.f));
      const int q3 = (int)rintf(fminf(fmaxf(sv[j].w * ia, -127.f), 127.f));
      const uint32_t d = (uint32_t)(q0 & 0xff) | ((uint32_t)(q1 & 0xff) << 8) |
                         ((uint32_t)(q2 & 0xff) << 16) | ((uint32_t)(q3 & 0xff) << 24);
      const int di   = j * 64 + lane;        // dword col 0..255
      const int ksw  = di >> 3;              // k-step 0..31
      const int h    = (di >> 2) & 1;        // 16B half within k-step
      const int slot = (tl & 31) + 32 * h;
      const int chunk = (mt * 32 + ksw) * 64 + (slot ^ (ksw & 7));
      *(uint32_t*)(&Af[nbuf][chunk * 16 + (di & 3) * 4]) = d;
    }
  };

  auto finish_group = [&](int nbuf) {
    const float4* sq4 = (const float4*)sq;
    float4 rs[4];
#pragma unroll
    for (int j = 0; j < 4; ++j) {
      const float4 s = sq4[j * 64 + lane];
      rs[j].x = __builtin_amdgcn_rcpf(s.x);
      rs[j].y = __builtin_amdgcn_rcpf(s.y);
      rs[j].z = __builtin_amdgcn_rcpf(s.z);
      rs[j].w = __builtin_amdgcn_rcpf(s.w);
    }
    quant_one(nbuf, qt0, xq0, rs);
    quant_one(nbuf, qt1, xq1, rs);
  };

#define GEMM8(BUF, KS0)                                                      \
  do {                                                                       \
    _Pragma("unroll")                                                        \
    for (int c = 0; c < 8; c += 2) {                                         \
      {                                                                      \
        const v4i a0 = ldA(BUF, 0, (KS0) + c, c);                            \
        const v4i a1 = ldA(BUF, 1, (KS0) + c, c);                            \
        __builtin_amdgcn_s_setprio(1);                                       \
        _Pragma("unroll")                                                    \
        for (int nt = 0; nt < 4; ++nt) {                                     \
          acc[0][nt] = MFMA_I8(a0, Ba[nt], acc[0][nt]);                      \
          acc[1][nt] = MFMA_I8(a1, Ba[nt], acc[1][nt]);                      \
        }                                                                    \
        __builtin_amdgcn_s_setprio(0);                                       \
        if ((KS0) + c + 2 < 32) {                                            \
          _Pragma("unroll")                                                  \
          for (int nt = 0; nt < 4; ++nt) Ba[nt] = ldB((KS0) + c + 2, nt);    \
        }                                                                    \
      }                                                                      \
      {                                                                      \
        const v4i a0 = ldA(BUF, 0, (KS0) + c + 1, c + 1);                    \
        const v4i a1 = ldA(BUF, 1, (KS0) + c + 1, c + 1);                    \
        __builtin_amdgcn_s_setprio(1);                                       \
        _Pragma("unroll")                                                    \
        for (int nt = 0; nt < 4; ++nt) {                                     \
          acc[0][nt] = MFMA_I8(a0, Bb[nt], acc[0][nt]);                      \
          acc[1][nt] = MFMA_I8(a1, Bb[nt], acc[1][nt]);                      \
        }                                                                    \
        __builtin_amdgcn_s_setprio(0);                                       \
        if ((KS0) + c + 3 < 32) {                                            \
          _Pragma("unroll")                                                  \
          for (int nt = 0; nt < 4; ++nt) Bb[nt] = ldB((KS0) + c + 3, nt);    \
        }                                                                    \
      }                                                                      \
    }                                                                        \
  } while (0)

  // ---- prologue: quantize tile 0 into Af[0] --------------------------------
  for (int g = 0; g < 4; ++g) {
    issue_group(base_t, g);
    finish_group(0);
  }
  __syncthreads();

  // ---- persistent tile loop ------------------------------------------------
#pragma unroll
  for (int it = 0; it < NTILES; ++it) {
    const int buf  = it & 1;
    const int nbuf = buf ^ 1;
    const int t0   = base_t + it * BM;
    const bool has_next = (it + 1 < NTILES);
    const int next_t0 = t0 + BM;

    // B ring init for ks = 0,1
#pragma unroll
    for (int nt = 0; nt < 4; ++nt) { Ba[nt] = ldB(0, nt); Bb[nt] = ldB(1, nt); }

    if (has_next) issue_group(next_t0, 0);
    GEMM8(buf, 0);
    if (has_next) { finish_group(nbuf); issue_group(next_t0, 1); }
    GEMM8(buf, 8);
    if (has_next) { finish_group(nbuf); issue_group(next_t0, 2); }
    GEMM8(buf, 16);
    if (has_next) { finish_group(nbuf); issue_group(next_t0, 3); }
    GEMM8(buf, 24);
    if (has_next) finish_group(nbuf);

    // ---- epilogue for tile it ---------------------------------------------
    // C/D layout: col = lane&31 (n), row = (reg&3)+8*(reg>>2)+4*(lane>>5)
#pragma unroll
    for (int mt = 0; mt < 2; ++mt) {
      float ascv[16];
#pragma unroll
      for (int reg = 0; reg < 16; ++reg)
        ascv[reg] =
            ascale_s[buf][mt * 32 + (reg & 3) + 8 * (reg >> 2) + 4 * (lane >> 5)];
#pragma unroll
      for (int nt = 0; nt < 4; ++nt) {
        const int n = w * 128 + nt * 32 + (lane & 31);
        const float wsc = wclip[n] * (1.f / 127.f);
        const float bs  = bias[n];
#pragma unroll
        for (int reg = 0; reg < 16; ++reg) {
          const int r = mt * 32 + (reg & 3) + 8 * (reg >> 2) + 4 * (lane >> 5);
          out[(size_t)(t0 + r) * NOUT + n] =
              (float)acc[mt][nt][reg] * ascv[reg] * wsc + bs;
        }
        // reset accumulator for the next tile
#pragma unroll
        for (int reg = 0; reg < 16; ++reg) acc[mt][nt][reg] = 0;
      }
    }
    __syncthreads();
  }
#undef GEMM8
}

// ---------------------------------------------------------------------------
extern "C" void kernel_launch(void* const* d_in, const int* in_sizes, int n_in,
                              void* d_out, int out_size, void* d_ws, size_t ws_size,
                              hipStream_t stream) {
  const float* x      = (const float*)d_in[0];
  const int*   weight = (const int*)d_in[1];
  const float* bias   = (const float*)d_in[2];
  const float* wclip  = (const float*)d_in[3];
  const float* sq     = (const float*)d_in[4];
  float* out = (float*)d_out;

  uint32_t* wfrag = (uint32_t*)d_ws;   // 1 MB fragment-ordered weight

  repack_w_frag<<<(NOUT * NIN / 16) / 256, 256, 0, stream>>>(weight, wfrag);
  fused_w8a8<<<T_TOK / (BM * NTILES), NTHR, 0, stream>>>(
      x, (const uint8_t*)wfrag, sq, wclip, bias, out);
}

// Round 7
// 100.602 us; speedup vs baseline: 1.3558x; 1.3558x over previous
//
#include <hip/hip_runtime.h>
#include <stdint.h>

// out[t][n] = (sum_k q8(x[t]/sq)[k] * w8[n][k]) * a_scale[t] * (wclip[n]/127) + bias[n]
#define T_TOK 32768
#define NIN   1024
#define NOUT  1024

typedef int   v4i  __attribute__((ext_vector_type(4)));
typedef int   v16i __attribute__((ext_vector_type(16)));
typedef float v4f  __attribute__((ext_vector_type(4)));

#define MFMA_I8(a, b, c) __builtin_amdgcn_mfma_i32_32x32x32_i8(a, b, c, 0, 0, 0)

// Fragment layout (both A and B): 16B chunk index = (tile32*32 + ks)*64 + slot
// where tile32 = row/32, slot = (row&31) + 32*khalf, holding rows' bytes
// k = ks*32 + khalf*16 .. +15.  A wave's MFMA operand load for (tile32, ks) is
// then one coalesced global_load_dwordx4 at base + lane*16.

// ---------------------------------------------------------------------------
// K0: repack weight (int32 [NOUT][NIN]) into fragment order. ~1.5 us.
// ---------------------------------------------------------------------------
__global__ __launch_bounds__(256) void repack_w_frag(const int* __restrict__ w,
                                                     uint32_t* __restrict__ wf) {
  const int gid  = blockIdx.x * 256 + threadIdx.x;  // 65536 chunks of 16B
  const int lane = gid & 63;
  const int ks   = (gid >> 6) & 31;
  const int nt   = gid >> 11;
  const int n    = nt * 32 + (lane & 31);
  const int kb   = ks * 32 + (lane >> 5) * 16;
  const int* src = w + (size_t)n * NIN + kb;
  uint32_t d[4];
#pragma unroll
  for (int q = 0; q < 4; ++q) {
    const int4 v = ((const int4*)src)[q];
    d[q] = (uint32_t)(v.x & 0xff) | ((uint32_t)(v.y & 0xff) << 8) |
           ((uint32_t)(v.z & 0xff) << 16) | ((uint32_t)(v.w & 0xff) << 24);
  }
  ((uint4*)wf)[gid] = make_uint4(d[0], d[1], d[2], d[3]);
}

// ---------------------------------------------------------------------------
// K1: smoothquant + per-token int8 quant, writing xq directly in fragment
// order (scattered 16B pieces; L2 write-back merges sectors — the 4 tokens
// sharing a 64B sector are processed by the same block within ~1 us).
// One wave per token, 4 tokens/block, r1's proven coalesced-read structure.
// ---------------------------------------------------------------------------
__global__ __launch_bounds__(256) void quant_frag(const float* __restrict__ x,
                                                  const float* __restrict__ sq,
                                                  uint32_t* __restrict__ afw,
                                                  float* __restrict__ asc) {
  const int lane = threadIdx.x & 63;
  const int wid  = threadIdx.x >> 6;
  const int tok  = blockIdx.x * 4 + wid;
  const v4f* xr = (const v4f*)(x + (size_t)tok * NIN);
  const v4f* sr = (const v4f*)sq;

  v4f xs[4];
  float m = 0.f;
#pragma unroll
  for (int j = 0; j < 4; ++j) {
    const int idx = j * 64 + lane;
    v4f xv = __builtin_nontemporal_load(&xr[idx]);   // x is read-once
    const v4f sv = sr[idx];
    xv.x *= __builtin_amdgcn_rcpf(sv.x);
    xv.y *= __builtin_amdgcn_rcpf(sv.y);
    xv.z *= __builtin_amdgcn_rcpf(sv.z);
    xv.w *= __builtin_amdgcn_rcpf(sv.w);
    xs[j] = xv;
    m = fmaxf(m, fmaxf(fmaxf(fabsf(xv.x), fabsf(xv.y)),
                       fmaxf(fabsf(xv.z), fabsf(xv.w))));
  }
#pragma unroll
  for (int off = 1; off < 64; off <<= 1) m = fmaxf(m, __shfl_xor(m, off));

  const float a_scale = fmaxf(m * (1.f / 127.f), 1e-8f);
  if (lane == 0) asc[tok] = a_scale;
  const float inv_a = __builtin_amdgcn_rcpf(a_scale);

  const int M = tok >> 5;        // 32-row tile
  const int r = tok & 31;
#pragma unroll
  for (int j = 0; j < 4; ++j) {
    const v4f v = xs[j];
    const int q0 = (int)rintf(fminf(fmaxf(v.x * inv_a, -127.f), 127.f));
    const int q1 = (int)rintf(fminf(fmaxf(v.y * inv_a, -127.f), 127.f));
    const int q2 = (int)rintf(fminf(fmaxf(v.z * inv_a, -127.f), 127.f));
    const int q3 = (int)rintf(fminf(fmaxf(v.w * inv_a, -127.f), 127.f));
    const uint32_t d = (uint32_t)(q0 & 0xff) | ((uint32_t)(q1 & 0xff) << 8) |
                       ((uint32_t)(q2 & 0xff) << 16) | ((uint32_t)(q3 & 0xff) << 24);
    const int di = j * 64 + lane;           // k-dword index 0..255
    const int ks = di >> 3;                 // k-step 0..31
    const int h  = (di >> 2) & 1;           // 16B half
    const int chunk = (M * 32 + ks) * 64 + r + 32 * h;
    afw[chunk * 4 + (di & 3)] = d;          // lands in L2, merges to sectors
  }
}

// ---------------------------------------------------------------------------
// K2: barrier-free, LDS-free int8 fragment GEMM.
// Block = 4 waves (2x2), tile 128t x 128n, K=1024 fully unrolled with a
// depth-4 static register ring (rule #20: all indices compile-time).
// Grid XCD-grouped: the 8 n-sibling blocks of each t-tile land on one XCD so
// A-fragments are read from that XCD's L2 after first touch.
// ---------------------------------------------------------------------------
__global__ __launch_bounds__(256, 3) void gemm_frag(
    const uint8_t* __restrict__ af,     // fragment-ordered xq, 32 MB
    const uint8_t* __restrict__ wf,     // fragment-ordered weight, 1 MB
    const float* __restrict__ asc,      // [T_TOK]
    const float* __restrict__ wclip,    // [NOUT]
    const float* __restrict__ bias,     // [NOUT]
    float* __restrict__ out)            // [T_TOK][NOUT]
{
  const int g   = blockIdx.x;           // 2048
  const int xcd = g & 7;
  const int j   = g >> 3;               // 0..255
  const int T   = xcd * 32 + (j >> 3);  // t-tile 0..255 (xcd-grouped)
  const int nb  = j & 7;                // n-tile 0..7

  const int tid  = threadIdx.x;
  const int lane = tid & 63;
  const int w    = tid >> 6;            // 0..3
  const int wr   = w >> 1, wc = w & 1;

  // wave-uniform fragment bases. A: tile32 = T*4 + wr*2 + mti (of 1024).
  // B: tile32 = nb*4 + wc*2 + nti (of 32).  [r6 bug: was nb*8 -> OOB reads]
  const uint8_t* Ab = af + ((size_t)(T * 4 + wr * 2) << 15) + lane * 16;
  const uint8_t* Bb = wf + ((size_t)(nb * 4 + wc * 2) << 15) + lane * 16;
  // per-ks stride: 64 chunks * 16B = 1024B; per-32tile stride: 32 KiB

  auto ldA = [&](int mti, int ks) -> v4i {
    return *(const v4i*)(Ab + mti * 32768 + ks * 1024);
  };
  auto ldB = [&](int nti, int ks) -> v4i {
    return *(const v4i*)(Bb + nti * 32768 + ks * 1024);
  };

  v16i acc[2][2] = {};
  v4i Ar[4][2], Br[4][2];
#pragma unroll
  for (int p = 0; p < 4; ++p) {
    Ar[p][0] = ldA(0, p); Ar[p][1] = ldA(1, p);
    Br[p][0] = ldB(0, p); Br[p][1] = ldB(1, p);
  }

#pragma unroll
  for (int ks = 0; ks < 32; ++ks) {
    const int p = ks & 3;               // static after unroll
    const v4i a0 = Ar[p][0], a1 = Ar[p][1];
    const v4i b0 = Br[p][0], b1 = Br[p][1];
    __builtin_amdgcn_s_setprio(1);
    acc[0][0] = MFMA_I8(a0, b0, acc[0][0]);
    acc[0][1] = MFMA_I8(a0, b1, acc[0][1]);
    acc[1][0] = MFMA_I8(a1, b0, acc[1][0]);
    acc[1][1] = MFMA_I8(a1, b1, acc[1][1]);
    __builtin_amdgcn_s_setprio(0);
    if (ks < 28) {
      Ar[p][0] = ldA(0, ks + 4); Ar[p][1] = ldA(1, ks + 4);
      Br[p][0] = ldB(0, ks + 4); Br[p][1] = ldB(1, ks + 4);
    }
  }

  // epilogue: C/D layout col = lane&31, row = (reg&3)+8*(reg>>2)+4*(lane>>5)
  const int t0 = T * 128 + wr * 64;
  const int nbase = nb * 128 + wc * 64;
  const int hr = 4 * (lane >> 5);
#pragma unroll
  for (int mt = 0; mt < 2; ++mt) {
    float ascv[16];
#pragma unroll
    for (int reg = 0; reg < 16; ++reg)
      ascv[reg] = asc[t0 + mt * 32 + (reg & 3) + 8 * (reg >> 2) + hr];
#pragma unroll
    for (int nt = 0; nt < 2; ++nt) {
      const int n = nbase + nt * 32 + (lane & 31);
      const float wsc = wclip[n] * (1.f / 127.f);
      const float bs  = bias[n];
#pragma unroll
      for (int reg = 0; reg < 16; ++reg) {
        const int rrow = t0 + mt * 32 + (reg & 3) + 8 * (reg >> 2) + hr;
        __builtin_nontemporal_store(
            (float)acc[mt][nt][reg] * ascv[reg] * wsc + bs,
            &out[(size_t)rrow * NOUT + n]);
      }
    }
  }
}

// ---------------------------------------------------------------------------
extern "C" void kernel_launch(void* const* d_in, const int* in_sizes, int n_in,
                              void* d_out, int out_size, void* d_ws, size_t ws_size,
                              hipStream_t stream) {
  const float* x      = (const float*)d_in[0];
  const int*   weight = (const int*)d_in[1];
  const float* bias   = (const float*)d_in[2];
  const float* wclip  = (const float*)d_in[3];
  const float* sq     = (const float*)d_in[4];
  float* out = (float*)d_out;

  // ws: wf 1 MB | af (fragment xq) 32 MB | asc 128 KB  => ~33.1 MB
  uint8_t* ws = (uint8_t*)d_ws;
  uint32_t* wfrag = (uint32_t*)ws;
  uint32_t* afrag = (uint32_t*)(ws + (1u << 20));
  float*    asc   = (float*)(ws + (1u << 20) + ((size_t)T_TOK * NIN));

  repack_w_frag<<<(NOUT * NIN / 16) / 256, 256, 0, stream>>>(weight, wfrag);
  quant_frag<<<T_TOK / 4, 256, 0, stream>>>(x, sq, afrag, asc);
  gemm_frag<<<2048, 256, 0, stream>>>((const uint8_t*)afrag,
                                      (const uint8_t*)wfrag,
                                      asc, wclip, bias, out);
}

// Round 8
// 91.450 us; speedup vs baseline: 1.4915x; 1.1001x over previous
//
#include <hip/hip_runtime.h>
#include <stdint.h>

// out[t][n] = (sum_k q8(x[t]/sq)[k] * w8[n][k]) * a_scale[t] * (wclip[n]/127) + bias[n]
#define T_TOK 32768
#define NIN   1024
#define NOUT  1024
#define BM    32      // tokens per block; block covers ALL 1024 outputs
#define NTHR  512     // 8 waves; wave w owns nt w*4..w*4+3 (128 n), all 32 tokens

typedef int   v4i  __attribute__((ext_vector_type(4)));
typedef int   v16i __attribute__((ext_vector_type(16)));
typedef float v4f  __attribute__((ext_vector_type(4)));

#define MFMA_I8(a, b, c) __builtin_amdgcn_mfma_i32_32x32x32_i8(a, b, c, 0, 0, 0)

// ---------------------------------------------------------------------------
// K0: repack weight (int32 [NOUT][NIN]) into MFMA fragment order:
//   chunk(nt,ks,lane) holds W[nt*32+(lane&31)][ks*32+(lane>>5)*16 .. +15]
// so a B-frag load is one coalesced global_load_dwordx4 at base + lane*16.
// (r3-verified)
// ---------------------------------------------------------------------------
__global__ __launch_bounds__(256) void repack_w_frag(const int* __restrict__ w,
                                                     uint32_t* __restrict__ wf) {
  const int gid  = blockIdx.x * 256 + threadIdx.x;  // 65536 chunks of 16B
  const int lane = gid & 63;
  const int ks   = (gid >> 6) & 31;
  const int nt   = gid >> 11;
  const int n    = nt * 32 + (lane & 31);
  const int kb   = ks * 32 + (lane >> 5) * 16;
  const int* src = w + (size_t)n * NIN + kb;
  uint32_t d[4];
#pragma unroll
  for (int q = 0; q < 4; ++q) {
    const int4 v = ((const int4*)src)[q];
    d[q] = (uint32_t)(v.x & 0xff) | ((uint32_t)(v.y & 0xff) << 8) |
           ((uint32_t)(v.z & 0xff) << 16) | ((uint32_t)(v.w & 0xff) << 24);
  }
  ((uint4*)wf)[gid] = make_uint4(d[0], d[1], d[2], d[3]);
}

// ---------------------------------------------------------------------------
// K1: fused quant + GEMM + dequant, sized for 2 blocks/CU so resident blocks
// overlap each other's HBM-read / L2-GEMM / HBM-write phases via TLP.
// LDS A fragment layout + ks-XOR swizzle (r3-verified): data for token tl,
// 16B-half h, k-step ks lives at chunk ks*64 + ((tl ^ (ks&7)) + 32h);
// read at lane ^ (ks&7) -> lane holds token lane&31, half lane>>5, and both
// write and read are bank-conflict-free.
// ---------------------------------------------------------------------------
__global__ __launch_bounds__(NTHR, 4) void fused_w8a8(
    const float* __restrict__ x,      // [T_TOK][NIN]
    const uint8_t* __restrict__ wf,   // fragment-ordered weight, 1 MB
    const float* __restrict__ sq,     // [NIN]
    const float* __restrict__ wclip,  // [NOUT]
    const float* __restrict__ bias,   // [NOUT]
    float* __restrict__ out)          // [T_TOK][NOUT]
{
  __shared__ __align__(16) uint8_t Af[BM * NIN];   // 32 KiB
  __shared__ float ascale_s[BM];

  const int tid  = threadIdx.x;
  const int lane = tid & 63;
  const int w    = tid >> 6;          // 0..7
  const int t0   = blockIdx.x * BM;

  // ---- quant: wave w quantizes tokens w*4 .. w*4+3 (r1/r3-verified) --------
  {
    const v4f* sq4 = (const v4f*)sq;
    v4f rs[4];
#pragma unroll
    for (int j = 0; j < 4; ++j) {
      const v4f s = sq4[j * 64 + lane];
      rs[j].x = __builtin_amdgcn_rcpf(s.x);
      rs[j].y = __builtin_amdgcn_rcpf(s.y);
      rs[j].z = __builtin_amdgcn_rcpf(s.z);
      rs[j].w = __builtin_amdgcn_rcpf(s.w);
    }
#pragma unroll
    for (int i = 0; i < 4; ++i) {
      const int tl = w * 4 + i;                       // 0..31
      const v4f* xr = (const v4f*)(x + (size_t)(t0 + tl) * NIN);
      v4f v[4];
      float m = 0.f;
#pragma unroll
      for (int j = 0; j < 4; ++j) {
        v4f a = __builtin_nontemporal_load(&xr[j * 64 + lane]);
        a.x *= rs[j].x; a.y *= rs[j].y; a.z *= rs[j].z; a.w *= rs[j].w;
        v[j] = a;
        m = fmaxf(m, fmaxf(fmaxf(fabsf(a.x), fabsf(a.y)),
                           fmaxf(fabsf(a.z), fabsf(a.w))));
      }
#pragma unroll
      for (int off = 1; off < 64; off <<= 1) m = fmaxf(m, __shfl_xor(m, off));
      const float as = fmaxf(m * (1.f / 127.f), 1e-8f);
      if (lane == 0) ascale_s[tl] = as;
      const float ia = __builtin_amdgcn_rcpf(as);
#pragma unroll
      for (int j = 0; j < 4; ++j) {
        const int q0 = (int)rintf(fminf(fmaxf(v[j].x * ia, -127.f), 127.f));
        const int q1 = (int)rintf(fminf(fmaxf(v[j].y * ia, -127.f), 127.f));
        const int q2 = (int)rintf(fminf(fmaxf(v[j].z * ia, -127.f), 127.f));
        const int q3 = (int)rintf(fminf(fmaxf(v[j].w * ia, -127.f), 127.f));
        const uint32_t d = (uint32_t)(q0 & 0xff) | ((uint32_t)(q1 & 0xff) << 8) |
                           ((uint32_t)(q2 & 0xff) << 16) | ((uint32_t)(q3 & 0xff) << 24);
        const int di   = j * 64 + lane;      // dword col 0..255
        const int ksw  = di >> 3;            // k-step 0..31
        const int h    = (di >> 2) & 1;      // 16B half
        const int slot = ((tl ^ (ksw & 7)) & 31) + 32 * h;
        *(uint32_t*)(&Af[(ksw * 64 + slot) * 16 + (di & 3) * 4]) = d;
      }
    }
  }

  // ---- B prologue (flies under the barrier wait) ---------------------------
  const uint8_t* wfw = wf + ((size_t)(w * 4) << 15);   // wave's 4 nt, 32KB each
  auto ldB = [&](int ks, int j) -> v4i {
    return *(const v4i*)(wfw + ((((j * 32 + ks) * 64) + lane) << 4));
  };
  v4i Ba0 = ldB(0, 0), Ba1 = ldB(0, 1), Ba2 = ldB(0, 2), Ba3 = ldB(0, 3);
  v4i Bb0 = ldB(1, 0), Bb1 = ldB(1, 1), Bb2 = ldB(1, 2), Bb3 = ldB(1, 3);

  __syncthreads();   // the ONLY barrier

  // ---- GEMM: 32 K-steps, 4 MFMA each; B ring depth 2 (named, rule #20) -----
  auto ldA = [&](int ks) -> v4i {
    return *(const v4i*)(&Af[((ks * 64) + (lane ^ (ks & 7))) << 4]);
  };

  v16i acc0 = {}, acc1 = {}, acc2 = {}, acc3 = {};

  for (int ks = 0; ks < 32; ks += 2) {
    {
      const v4i a = ldA(ks);
      __builtin_amdgcn_s_setprio(1);
      acc0 = MFMA_I8(a, Ba0, acc0);
      acc1 = MFMA_I8(a, Ba1, acc1);
      acc2 = MFMA_I8(a, Ba2, acc2);
      acc3 = MFMA_I8(a, Ba3, acc3);
      __builtin_amdgcn_s_setprio(0);
      if (ks + 2 < 32) {
        Ba0 = ldB(ks + 2, 0); Ba1 = ldB(ks + 2, 1);
        Ba2 = ldB(ks + 2, 2); Ba3 = ldB(ks + 2, 3);
      }
    }
    {
      const v4i a = ldA(ks + 1);
      __builtin_amdgcn_s_setprio(1);
      acc0 = MFMA_I8(a, Bb0, acc0);
      acc1 = MFMA_I8(a, Bb1, acc1);
      acc2 = MFMA_I8(a, Bb2, acc2);
      acc3 = MFMA_I8(a, Bb3, acc3);
      __builtin_amdgcn_s_setprio(0);
      if (ks + 3 < 32) {
        Bb0 = ldB(ks + 3, 0); Bb1 = ldB(ks + 3, 1);
        Bb2 = ldB(ks + 3, 2); Bb3 = ldB(ks + 3, 3);
      }
    }
  }

  // ---- epilogue: C/D layout col = lane&31, row = (reg&3)+8*(reg>>2)+4*(lane>>5)
  const int hr = 4 * (lane >> 5);
  float ascv[16];
#pragma unroll
  for (int reg = 0; reg < 16; ++reg)
    ascv[reg] = ascale_s[(reg & 3) + 8 * (reg >> 2) + hr];

#define EPI(ACC, NTL)                                                        \
  do {                                                                       \
    const int n = w * 128 + (NTL) * 32 + (lane & 31);                        \
    const float wsc = wclip[n] * (1.f / 127.f);                              \
    const float bs  = bias[n];                                               \
    _Pragma("unroll")                                                        \
    for (int reg = 0; reg < 16; ++reg) {                                     \
      const int r = (reg & 3) + 8 * (reg >> 2) + hr;                         \
      __builtin_nontemporal_store(                                           \
          (float)ACC[reg] * ascv[reg] * wsc + bs,                            \
          &out[(size_t)(t0 + r) * NOUT + n]);                                \
    }                                                                        \
  } while (0)

  EPI(acc0, 0);
  EPI(acc1, 1);
  EPI(acc2, 2);
  EPI(acc3, 3);
#undef EPI
}

// ---------------------------------------------------------------------------
extern "C" void kernel_launch(void* const* d_in, const int* in_sizes, int n_in,
                              void* d_out, int out_size, void* d_ws, size_t ws_size,
                              hipStream_t stream) {
  const float* x      = (const float*)d_in[0];
  const int*   weight = (const int*)d_in[1];
  const float* bias   = (const float*)d_in[2];
  const float* wclip  = (const float*)d_in[3];
  const float* sq     = (const float*)d_in[4];
  float* out = (float*)d_out;

  uint32_t* wfrag = (uint32_t*)d_ws;   // 1 MB fragment-ordered weight

  repack_w_frag<<<(NOUT * NIN / 16) / 256, 256, 0, stream>>>(weight, wfrag);
  fused_w8a8<<<T_TOK / BM, NTHR, 0, stream>>>(x, (const uint8_t*)wfrag,
                                              sq, wclip, bias, out);
}